// Round 7
// baseline (143.968 us; speedup 1.0000x reference)
//
#include <hip/hip_runtime.h>

#define IF 212445
#define N1 65536
#define N2 16384
#define NCLS 20
#define BATCH 32
#define HISTB 32
#define MCHUNK 1024
#define MBLK ((IF + MCHUNK - 1) / MCHUNK)     // 208
#define TCHUNK 2048
#define NCH ((IF + TCHUNK - 1) / TCHUNK)      // 104
#define GRIDM (8 * NCH)                        // 832 = 8 row-quads x 104 chunks

// ws layout (bytes, all 16B aligned):
#define OFF_T3   0        // float[32*128]  zeroed by k_setup
#define OFF_HIST 16400    // int[32*256]    per-block partial counts (written)
#define OFF_A    49168    // float[20*128]
#define OFF_SV   59408    // float[20*128]
#define OFF_SW   69648    // float[20*128]
#define OFF_CP   79888    // float[20]
#define OFF_MIDX 79968    // int[IF]

// Launch 1: 261 blocks (unchanged — never the bottleneck).
__global__ __launch_bounds__(256) void k_setup(
    const float* __restrict__ W0, const float* __restrict__ b0,
    const float* __restrict__ W1, const float* __restrict__ b1,
    const float* __restrict__ W2, const float* __restrict__ b2,
    const float* __restrict__ fc_w, const float* __restrict__ fc_b,
    const int* __restrict__ p0, const int* __restrict__ p1,
    const int* __restrict__ p2, char* __restrict__ ws)
{
    int t = threadIdx.x, b = blockIdx.x;
    float* t3   = (float*)(ws + OFF_T3);
    int*   hist = (int*)(ws + OFF_HIST);
    float* A    = (float*)(ws + OFF_A);
    float* Sv   = (float*)(ws + OFF_SV);
    float* Sw   = (float*)(ws + OFF_SW);
    float* CP   = (float*)(ws + OFF_CP);
    int*   midx = (int*)(ws + OFF_MIDX);

    if (b < MBLK) {
        int i = b * MCHUNK + 4 * t;
        if (i + 3 < IF) {
            int4 p = *(const int4*)(p0 + i);
            int4 r;
            r.x = p2[p1[p.x]]; r.y = p2[p1[p.y]];
            r.z = p2[p1[p.z]]; r.w = p2[p1[p.w]];
            *(int4*)(midx + i) = r;
        } else {
            for (int j = i; j < IF; ++j) midx[j] = p2[p1[p0[j]]];
        }
    } else if (b == MBLK) {
        for (int s = t; s < BATCH * 128; s += 256) t3[s] = 0.f;
    } else if (b < MBLK + 1 + HISTB) {
        int hb = b - (MBLK + 1);
        __shared__ int hA[128], hB[128];
        if (t < 128) { hA[t] = 0; hB[t] = 0; }
        __syncthreads();
        const int total = N1 + N2;
        for (int idx = hb * 256 + t; idx < total; idx += HISTB * 256) {
            if (idx < N1) atomicAdd(&hA[p2[p1[idx]]], 1);
            else          atomicAdd(&hB[p2[idx - N1]], 1);
        }
        __syncthreads();
        hist[hb * 256 + t] = (t < 128) ? hA[t] : hB[t - 128];
    } else {
        int cls = b - (MBLK + 1 + HISTB);
        __shared__ float su1[64], sv1[64];
        __shared__ float su2[128], sv2[128], sw2[128], sb2[128];
        __shared__ float pA[256], pV[256], pW[256], pB[256];
        if (t < 64) {
            float a = 0.f, bb = 0.f;
            for (int c = 0; c < 32; ++c) {
                float w = W1[t * 32 + c];
                a += w * W0[c]; bb += w * b0[c];   // W0 is (32,1)
            }
            su1[t] = a; sv1[t] = bb;
        }
        if (t >= 128) sb2[t - 128] = b2[t - 128];
        __syncthreads();
        if (t < 128) {
            float a = 0.f, bb = 0.f, c = 0.f;
            for (int j = 0; j < 64; ++j) {
                float w = W2[t * 64 + j];
                a += w * su1[j]; bb += w * sv1[j]; c += w * b1[j];
            }
            su2[t] = a; sv2[t] = bb; sw2[t] = c;
        }
        __syncthreads();
        int m = t & 127, h = t >> 7;
        const float* fw = fc_w + cls * 16384 + m;
        float Sa = 0.f, SvA = 0.f, SwA = 0.f, SbA = 0.f;
        #pragma unroll 8
        for (int o = h * 64; o < h * 64 + 64; ++o) {
            float w = fw[o * 128];
            Sa += w * su2[o]; SvA += w * sv2[o];
            SwA += w * sw2[o]; SbA += w * sb2[o];
        }
        pA[t] = Sa; pV[t] = SvA; pW[t] = SwA; pB[t] = SbA;
        __syncthreads();
        if (t < 128) {
            A [cls * 128 + t] = pA[t] + pA[t + 128];
            Sv[cls * 128 + t] = pV[t] + pV[t + 128];
            Sw[cls * 128 + t] = pW[t] + pW[t + 128];
            pB[t] = pB[t] + pB[t + 128];
        }
        __syncthreads();
        for (int s2 = 64; s2 > 0; s2 >>= 1) {
            if (t < s2) pB[t] += pB[t + s2];
            __syncthreads();
        }
        if (t == 0) CP[cls] = fc_b[cls] + pB[0];
    }
}

// Launch 2: pure scatter-reduce. 832 blocks, 8 KB LDS, NO device fences,
// NO contended single-address atomics. Flush = relaxed device atomicAdd
// spread over 4096 distinct t3 addresses.
__global__ __launch_bounds__(256) void k_main(
    const float* __restrict__ x, const int* __restrict__ midx,
    float* __restrict__ t3)
{
    __shared__ float hist[4][512];   // 8 KB: per-wave private 4 rows x 128 bins
    int t = threadIdx.x;
    for (int s = t; s < 2048; s += 256) ((float*)hist)[s] = 0.f;
    __syncthreads();

    int g = blockIdx.x & 7, chunk = blockIdx.x >> 3;
    int r0 = g * 4, base = chunk * TCHUNK;
    const float* x0 = x + (size_t)(r0 + 0) * IF;
    const float* x1 = x + (size_t)(r0 + 1) * IF;
    const float* x2 = x + (size_t)(r0 + 2) * IF;
    const float* x3 = x + (size_t)(r0 + 3) * IF;
    float* hw = &hist[t >> 6][0];

    if (base + TCHUNK <= IF) {
        #pragma unroll 1
        for (int k = 0; k < TCHUNK / 1024; ++k) {   // 2 outer iters
            float v0[4], v1[4], v2[4], v3[4]; int mi[4];
            int i0 = base + k * 1024 + t;
            #pragma unroll
            for (int u = 0; u < 4; ++u) {
                int i = i0 + u * 256;
                mi[u] = midx[i];
                v0[u] = x0[i]; v1[u] = x1[i]; v2[u] = x2[i]; v3[u] = x3[i];
            }
            #pragma unroll
            for (int u = 0; u < 4; ++u) {
                atomicAdd(&hw[      mi[u]], v0[u]);
                atomicAdd(&hw[128 + mi[u]], v1[u]);
                atomicAdd(&hw[256 + mi[u]], v2[u]);
                atomicAdd(&hw[384 + mi[u]], v3[u]);
            }
        }
    } else {
        for (int i = base + t; i < IF; i += 256) {
            int m = midx[i];
            atomicAdd(&hw[      m], x0[i]);
            atomicAdd(&hw[128 + m], x1[i]);
            atomicAdd(&hw[256 + m], x2[i]);
            atomicAdd(&hw[384 + m], x3[i]);
        }
    }
    __syncthreads();
    for (int s = t; s < 512; s += 256) {
        float v = hist[0][s] + hist[1][s] + hist[2][s] + hist[3][s];
        atomicAdd(&t3[(r0 + (s >> 7)) * 128 + (s & 127)], v);
    }
}

// Launch 3: epilogue, single block of 256.
__global__ __launch_bounds__(256) void k_epi(
    char* __restrict__ ws, float* __restrict__ out)
{
    __shared__ float smem[7424];
    int t = threadIdx.x;
    const float* t3   = (const float*)(ws + OFF_T3);
    const int*   hist = (const int*)(ws + OFF_HIST);
    const float* A    = (const float*)(ws + OFF_A);
    const float* Svt  = (const float*)(ws + OFF_SV);
    const float* Swt  = (const float*)(ws + OFF_SW);
    const float* CP   = (const float*)(ws + OFF_CP);

    float* st3   = smem;          // [m*33 + n]   4224 floats
    float* sA    = smem + 4224;   // [m*20 + cls] 2560
    float* c2f   = smem + 6784;   // 128
    float* cnf   = smem + 6912;   // 128
    float* cpart = smem + 7040;   // 160
    float* scst  = smem + 7200;   // 20

    #pragma unroll
    for (int k = 0; k < 16; ++k) {
        int s = t + 256 * k;
        st3[(s & 127) * 33 + (s >> 7)] = t3[s];
    }
    #pragma unroll
    for (int k = 0; k < 10; ++k) {
        int q = t + 256 * k;
        sA[(q & 127) * 20 + (q >> 7)] = A[q];
    }
    {
        int acc = 0;
        #pragma unroll
        for (int h = 0; h < HISTB; ++h) acc += hist[h * 256 + t];
        if (t < 128) c2f[t] = (float)acc; else cnf[t - 128] = (float)acc;
    }
    __syncthreads();
    if (t < 160) {
        int cls = t >> 3, m0 = (t & 7) * 16;
        const float* sv = Svt + cls * 128;
        const float* sw = Swt + cls * 128;
        float s = 0.f;
        #pragma unroll
        for (int m = m0; m < m0 + 16; ++m)
            s += c2f[m] * sv[m] + cnf[m] * sw[m];
        cpart[t] = s;
    }
    __syncthreads();
    if (t < NCLS) {
        float s = CP[t];
        #pragma unroll
        for (int k = 0; k < 8; ++k) s += cpart[t * 8 + k];
        scst[t] = s;
    }
    __syncthreads();
    #pragma unroll
    for (int k = 0; k < 3; ++k) {
        int p = t + 256 * k;
        if (p < BATCH * NCLS) {
            int n = p / NCLS, cls = p - n * NCLS;
            float acc = scst[cls];
            #pragma unroll 8
            for (int m = 0; m < 128; ++m)
                acc += sA[m * 20 + cls] * st3[m * 33 + n];
            out[p] = acc;
        }
    }
}

extern "C" void kernel_launch(void* const* d_in, const int* in_sizes, int n_in,
                              void* d_out, int out_size, void* d_ws, size_t ws_size,
                              hipStream_t stream)
{
    const float* x    = (const float*)d_in[0];
    const float* W0   = (const float*)d_in[1];
    const float* b0   = (const float*)d_in[2];
    const float* W1   = (const float*)d_in[3];
    const float* b1   = (const float*)d_in[4];
    const float* W2   = (const float*)d_in[5];
    const float* b2   = (const float*)d_in[6];
    const float* fc_w = (const float*)d_in[7];
    const float* fc_b = (const float*)d_in[8];
    const int*   p0   = (const int*)d_in[9];
    const int*   p1   = (const int*)d_in[10];
    const int*   p2   = (const int*)d_in[11];

    char* ws = (char*)d_ws;
    int*  midx = (int*)(ws + OFF_MIDX);
    float* t3  = (float*)(ws + OFF_T3);

    k_setup<<<MBLK + 1 + HISTB + NCLS, 256, 0, stream>>>(
        W0, b0, W1, b1, W2, b2, fc_w, fc_b, p0, p1, p2, ws);
    k_main<<<GRIDM, 256, 0, stream>>>(x, midx, t3);
    k_epi<<<1, 256, 0, stream>>>(ws, (float*)d_out);
}